// Round 1
// 744.677 us; speedup vs baseline: 1.0354x; 1.0354x over previous
//
#include <hip/hip_runtime.h>
#include <hip/hip_bf16.h>
#include <stdint.h>

typedef __bf16 bf16;
typedef __attribute__((ext_vector_type(8))) __bf16 bf16x8;
typedef __attribute__((ext_vector_type(4))) __bf16 bf16x4;
typedef __attribute__((ext_vector_type(4))) float f32x4;

#define B_ 2
#define F_ 128
#define P_ 256
#define H_ 8
#define D_ 64
#define DIM_ 512
#define NROWS (B_*F_*P_)   // 65536

// async global->LDS, 16B per lane. LDS dest must be wave-uniform base + lane*16.
__device__ __forceinline__ void load_lds16(const void* g, void* l) {
  __builtin_amdgcn_global_load_lds(
      (__attribute__((address_space(1))) void*)(uintptr_t)g,
      (__attribute__((address_space(3))) void*)(uint32_t)(uintptr_t)l,
      16, 0, 0);
}

// fp32 -> bf16 cast, 8 elements/thread (n must be a multiple of 8)
__global__ void cvt_f32_bf16(const float* __restrict__ src, bf16* __restrict__ dst, int n)
{
  int i = (blockIdx.x * 256 + threadIdx.x) * 8;
  if (i < n) {
    float4 a = *(const float4*)(src + i);
    float4 b = *(const float4*)(src + i + 4);
    bf16x8 o;
    o[0] = (bf16)a.x; o[1] = (bf16)a.y; o[2] = (bf16)a.z; o[3] = (bf16)a.w;
    o[4] = (bf16)b.x; o[5] = (bf16)b.y; o[6] = (bf16)b.z; o[7] = (bf16)b.w;
    *(bf16x8*)(dst + i) = o;
  }
}

// W_o fp32 [512(he)][512(d)] -> wot bf16 [512(d)][512(he)]
__global__ void transpose_wo(const float* __restrict__ src, bf16* __restrict__ dst)
{
  int idx = blockIdx.x * 256 + threadIdx.x;
  int d = idx & 511, he = idx >> 9;
  dst[(size_t)d * 512 + he] = (bf16)src[(size_t)he * 512 + d];
}

// ---------------------------------------------------------------------------
// gemm256: C[M x N] = A[M x K=512] * Bt[N x K]^T + bias[N]
// 256x256 tile, BK=32, 8 waves (2M x 4N), 512 threads, 128 KiB LDS.
// 4-buffer LDS pipeline, prefetch depth 3, counted vmcnt (never drained to 0
// in steady state), raw s_barrier, setprio(1) around MFMA clusters.
// LDS k-octet swizzle g(row)=(row>>1)&3 applied on the GLOBAL source
// (linear global_load_lds dest) + on the ds_read side -> conflict-free b128.
// XCD-chunked block swizzle, N-fast within chunk (A-panel reuse in L2).
// ---------------------------------------------------------------------------
template <typename OutT, int NT>
__global__ __launch_bounds__(512, 2)
void gemm256(const bf16* __restrict__ A, const bf16* __restrict__ Bt,
             const float* __restrict__ bias, OutT* __restrict__ C)
{
  constexpr int K = 512;
  constexpr int N = NT * 256;
  constexpr int NTILES = 16;              // K / 32
  __shared__ __align__(16) bf16 As[4][256 * 32];
  __shared__ __align__(16) bf16 Bs[4][256 * 32];

  const int t    = threadIdx.x;
  const int lane = t & 63;
  const int l16  = lane & 15;
  const int qd   = lane >> 4;
  const int wave = t >> 6;
  const int wm   = wave >> 2;             // 0..1  (M half)
  const int wn   = wave & 3;              // 0..3  (N quarter)

  // XCD-aware swizzle: NWG/8 consecutive logical blocks per XCD, N-fast.
  constexpr int NWG = NT * 256;
  const int logical = (blockIdx.x & 7) * (NWG / 8) + (blockIdx.x >> 3);
  const int mBase = (logical / NT) * 256;
  const int nBase = (logical % NT) * 256;

  // staging: slot c = r*512 + t (16B each), row = c>>2 (+128 for r=1),
  // global k-octet pre-swizzled by g(row) = (row>>1)&3 (same for both r).
  const int srow = t >> 2;
  const int soct = (((t & 3) ^ ((srow >> 1) & 3)) << 3);
  const bf16* aS0 = A  + (size_t)(mBase + srow)       * K + soct;
  const bf16* aS1 = A  + (size_t)(mBase + srow + 128) * K + soct;
  const bf16* bS0 = Bt + (size_t)(nBase + srow)       * K + soct;
  const bf16* bS1 = Bt + (size_t)(nBase + srow + 128) * K + soct;
  const int dst = t * 8;                  // elems; *2B = lane-linear 16B slots

#define STAGE_A(tt) do { \
    load_lds16(aS0 + (tt) * 32, &As[(tt) & 3][dst]); \
    load_lds16(aS1 + (tt) * 32, &As[(tt) & 3][4096 + dst]); } while (0)
#define STAGE_B(tt) do { \
    load_lds16(bS0 + (tt) * 32, &Bs[(tt) & 3][dst]); \
    load_lds16(bS1 + (tt) * 32, &Bs[(tt) & 3][4096 + dst]); } while (0)

  // fragment read: row = (warp rows) + l16, octet qd, swizzled by g(row);
  // g(row) reduces to (l16>>1)&3 for every fragment (other terms ≡0 mod 4).
  const int swz = ((qd ^ ((l16 >> 1) & 3)) << 3);
  const bf16* aRd = &As[0][(wm * 128 + l16) * 32 + swz];
  const bf16* bRd = &Bs[0][(wn * 64  + l16) * 32 + swz];

  f32x4 acc[8][4] = {};

  // prologue: tiles 0..2 in flight (12 gloads/wave)
  STAGE_A(0); STAGE_B(0); STAGE_A(1); STAGE_B(1); STAGE_A(2); STAGE_B(2);

#define MF(i, j, av, bv) \
  acc[i][j] = __builtin_amdgcn_mfma_f32_16x16x32_bf16(av, bv, acc[i][j], 0, 0, 0)

#pragma unroll
  for (int tt = 0; tt < NTILES; ++tt) {
    // stage A of tile tt+3 (overwrites tile tt-1's A: all waves passed the
    // end-of-iter barrier of tt-1, so its reads are complete).
    if (tt + 3 < NTILES) STAGE_A(tt + 3);
    // counted wait: newest 10 outstanding = A/B(tt+1), A/B(tt+2), A(tt+3);
    // everything older (incl. tile tt) retired. Tail shrinks the count.
    if      (tt <= NTILES - 4) asm volatile("s_waitcnt vmcnt(10)" ::: "memory");
    else if (tt == NTILES - 3) asm volatile("s_waitcnt vmcnt(8)"  ::: "memory");
    else if (tt == NTILES - 2) asm volatile("s_waitcnt vmcnt(4)"  ::: "memory");
    else                       asm volatile("s_waitcnt vmcnt(0)"  ::: "memory");
    __builtin_amdgcn_s_barrier();
    asm volatile("" ::: "memory");

    const bf16* aB = aRd + (tt & 3) * (256 * 32);
    const bf16* bB = bRd + (tt & 3) * (256 * 32);

    // phase 1: b[0..3] + a[0..3] (8 x ds_read_b128), 16 MFMA
    bf16x8 a[4], b[4];
#pragma unroll
    for (int j = 0; j < 4; ++j) b[j] = *(const bf16x8*)(bB + j * 512);
#pragma unroll
    for (int i = 0; i < 4; ++i) a[i] = *(const bf16x8*)(aB + i * 512);
    __builtin_amdgcn_s_setprio(1);
#pragma unroll
    for (int i = 0; i < 4; ++i)
#pragma unroll
      for (int j = 0; j < 4; ++j) MF(i, j, a[i], b[j]);
    __builtin_amdgcn_s_setprio(0);
    __builtin_amdgcn_s_barrier();
    asm volatile("" ::: "memory");

    // phase 2: stage B(tt+3), a[4..7] (4 x ds_read_b128), 16 MFMA
    if (tt + 3 < NTILES) STAGE_B(tt + 3);
#pragma unroll
    for (int i = 0; i < 4; ++i) a[i] = *(const bf16x8*)(aB + (4 + i) * 512);
    __builtin_amdgcn_s_setprio(1);
#pragma unroll
    for (int i = 0; i < 4; ++i)
#pragma unroll
      for (int j = 0; j < 4; ++j) MF(4 + i, j, a[i], b[j]);
    __builtin_amdgcn_s_setprio(0);
    __builtin_amdgcn_s_barrier();
    asm volatile("" ::: "memory");
  }
#undef STAGE_A
#undef STAGE_B
#undef MF

  // epilogue: D row = qd*4 + r within each 16x16 tile, col = l16
#pragma unroll
  for (int j = 0; j < 4; ++j) {
    const int coln = nBase + wn * 64 + j * 16 + l16;
    const float bv = bias[coln];
#pragma unroll
    for (int i = 0; i < 8; ++i) {
      const int rowm = mBase + wm * 128 + i * 16 + qd * 4;
#pragma unroll
      for (int r = 0; r < 4; ++r)
        C[(size_t)(rowm + r) * N + coln] = (OutT)(acc[i][j][r] + bv);
    }
  }
}

// ---------------------------------------------------------------------------
// Attention v2: S^T = K·Q^T (C layout: row=key, col=q), softmax in registers,
// O^T = V^T·P^T. Q/K fragments loaded straight from global (b128, no LDS).
// LDS: Vt[64][VS] (V transposed, padded) + Pq[128][136] (wave-private P rows).
// One __syncthreads total. NKT = key tiles of 16 (8 frame / 16 point).
// ---------------------------------------------------------------------------
template <int NKT, int MODE, int VS>
__global__ __launch_bounds__(256, 2)
void attn2(const bf16* __restrict__ qkv, bf16* __restrict__ outp)
{
  __shared__ __align__(16) bf16 Vt[64 * VS];
  __shared__ __align__(16) bf16 Pq[128 * 136];

  const int t    = threadIdx.x;
  const int lane = t & 63;
  const int wave = t >> 6;
  const int l16  = lane & 15;
  const int qd   = lane >> 4;

  const int bid = blockIdx.x;
  int h, q0, rowbase, rstride;
  if (MODE == 0) {
    h = bid & 7;
    int p = (bid >> 3) & (P_ - 1);
    int b = bid >> 11;
    rowbase = b * F_ * P_ + p; rstride = P_; q0 = 0;
  } else {
    int qb = bid & 1;
    h = (bid >> 1) & 7;
    int f = (bid >> 4) & (F_ - 1);
    int b = bid >> 11;
    rowbase = (b * F_ + f) * P_; rstride = 1; q0 = qb * 128;
  }

  // ---- stage V^T into LDS: Vt[e][key], padded stride VS ----
#pragma unroll
  for (int p = 0; p < NKT / 8; ++p) {
    int key = p * 128 + (t >> 1);
    int eh  = (t & 1) * 32;
    const bf16* src = qkv + (size_t)(rowbase + key * rstride) * 1536 + 1024 + h * 64 + eh;
    bf16x8 v[4];
#pragma unroll
    for (int jj = 0; jj < 4; ++jj) v[jj] = *(const bf16x8*)(src + jj * 8);
#pragma unroll
    for (int jj = 0; jj < 4; ++jj)
#pragma unroll
      for (int j = 0; j < 8; ++j)
        Vt[(eh + jj * 8 + j) * VS + key] = v[jj][j];
  }

  // ---- Q fragments (wave owns q columns wave*32..+31), direct global ----
  const int qloc = wave * 32;
  bf16x8 qf[2][2];
#pragma unroll
  for (int qt = 0; qt < 2; ++qt)
#pragma unroll
    for (int ks = 0; ks < 2; ++ks)
      qf[qt][ks] = *(const bf16x8*)(qkv +
          (size_t)(rowbase + (q0 + qloc + qt * 16 + l16) * rstride) * 1536 +
          h * 64 + ks * 32 + qd * 8);

  // ---- S^T = K·Q^T : K fragments direct from global ----
  f32x4 sacc[NKT][2] = {};
#pragma unroll
  for (int tn = 0; tn < NKT; ++tn) {
    const bf16* krow = qkv + (size_t)(rowbase + (tn * 16 + l16) * rstride) * 1536 + 512 + h * 64;
    bf16x8 kf0 = *(const bf16x8*)(krow + qd * 8);
    bf16x8 kf1 = *(const bf16x8*)(krow + 32 + qd * 8);
#pragma unroll
    for (int qt = 0; qt < 2; ++qt) {
      sacc[tn][qt] = __builtin_amdgcn_mfma_f32_16x16x32_bf16(kf0, qf[qt][0], sacc[tn][qt], 0, 0, 0);
      sacc[tn][qt] = __builtin_amdgcn_mfma_f32_16x16x32_bf16(kf1, qf[qt][1], sacc[tn][qt], 0, 0, 0);
    }
  }

  // ---- softmax over keys (rows of S^T): in-lane (tn,r) + shfl over qd ----
#pragma unroll
  for (int qt = 0; qt < 2; ++qt) {
    float m = -3.0e38f;
#pragma unroll
    for (int tn = 0; tn < NKT; ++tn)
#pragma unroll
      for (int r = 0; r < 4; ++r) m = fmaxf(m, sacc[tn][qt][r]);
    m = fmaxf(m, __shfl_xor(m, 16));
    m = fmaxf(m, __shfl_xor(m, 32));
    float s = 0.0f;
#pragma unroll
    for (int tn = 0; tn < NKT; ++tn)
#pragma unroll
      for (int r = 0; r < 4; ++r) {
        float e0 = __expf(sacc[tn][qt][r] - m);
        sacc[tn][qt][r] = e0;
        s += e0;
      }
    s += __shfl_xor(s, 16);
    s += __shfl_xor(s, 32);
    float inv = 1.0f / s;
#pragma unroll
    for (int tn = 0; tn < NKT; ++tn)
#pragma unroll
      for (int r = 0; r < 4; ++r) sacc[tn][qt][r] *= inv;
  }

  // ---- O^T = V^T·P^T, key-halves of 128; Pq rows are wave-private ----
  f32x4 oacc[4][2] = {};
#pragma unroll
  for (int hf = 0; hf < NKT / 8; ++hf) {
    // pack P rows (4 consecutive keys per lane) into Pq[q][key_local], b64
#pragma unroll
    for (int qt = 0; qt < 2; ++qt)
#pragma unroll
      for (int tl = 0; tl < 8; ++tl) {
        int tn = hf * 8 + tl;
        bf16x4 pk;
#pragma unroll
        for (int r = 0; r < 4; ++r) pk[r] = (bf16)sacc[tn][qt][r];
        *(bf16x4*)(Pq + (qloc + qt * 16 + l16) * 136 + tl * 16 + qd * 4) = pk;
      }
    if (hf == 0) __syncthreads();   // Vt ready; Pq needs no cross-wave sync
#pragma unroll
    for (int ks = 0; ks < 4; ++ks) {
      bf16x8 pf[2];
#pragma unroll
      for (int qt = 0; qt < 2; ++qt)
        pf[qt] = *(const bf16x8*)(Pq + (qloc + qt * 16 + l16) * 136 + ks * 32 + qd * 8);
#pragma unroll
      for (int te = 0; te < 4; ++te) {
        bf16x8 vf = *(const bf16x8*)(Vt + (te * 16 + l16) * VS + hf * 128 + ks * 32 + qd * 8);
#pragma unroll
        for (int qt = 0; qt < 2; ++qt)
          oacc[te][qt] = __builtin_amdgcn_mfma_f32_16x16x32_bf16(vf, pf[qt], oacc[te][qt], 0, 0, 0);
      }
    }
  }

  // ---- store O^T: lane holds rows e=te*16+qd*4..+3, col q -> b64 stores ----
#pragma unroll
  for (int te = 0; te < 4; ++te)
#pragma unroll
    for (int qt = 0; qt < 2; ++qt) {
      int q = q0 + qloc + qt * 16 + l16;
      bf16x4 pk;
#pragma unroll
      for (int r = 0; r < 4; ++r) pk[r] = (bf16)oacc[te][qt][r];
      *(bf16x4*)(outp + (size_t)(rowbase + q * rstride) * 512 + h * 64 + te * 16 + qd * 4) = pk;
    }
}

extern "C" void kernel_launch(void* const* d_in, const int* in_sizes, int n_in,
                              void* d_out, int out_size, void* d_ws, size_t ws_size,
                              hipStream_t stream)
{
  (void)in_sizes; (void)n_in; (void)out_size; (void)ws_size;
  const float* x   = (const float*)d_in[0];   // [B,F,P,512] fp32
  const float* Wf  = (const float*)d_in[1];   // [3,8,64,512] fp32
  const float* bfb = (const float*)d_in[2];   // [1536] fp32
  const float* Wp  = (const float*)d_in[3];   // [3,8,64,8,64] fp32
  const float* bpb = (const float*)d_in[4];   // [1536] fp32
  const float* Wo  = (const float*)d_in[5];   // [8,64,512] fp32
  const float* bob = (const float*)d_in[6];   // [512] fp32
  float* out = (float*)d_out;                 // fp32 output

  char* ws = (char*)d_ws;
  bf16* qkv = (bf16*)ws;                                   // 65536x1536 (reused)
  bf16* fa  = (bf16*)(ws + (size_t)NROWS * 1536 * 2);      // 65536x512 (xb/fa/pa)
  bf16* xb  = fa;
  char* wbase = ws + (size_t)NROWS * 1536 * 2 + (size_t)NROWS * 512 * 2;
  bf16* wfb = (bf16*)wbase;
  bf16* wpb = (bf16*)(wbase + 1536 * 512 * 2);
  bf16* wot = (bf16*)(wbase + 2 * 1536 * 512 * 2);

  cvt_f32_bf16<<<(NROWS * 512) / (256 * 8), 256, 0, stream>>>(x, xb, NROWS * 512);
  cvt_f32_bf16<<<(1536 * 512) / (256 * 8), 256, 0, stream>>>(Wf, wfb, 1536 * 512);
  cvt_f32_bf16<<<(1536 * 512) / (256 * 8), 256, 0, stream>>>(Wp, wpb, 1536 * 512);
  transpose_wo<<<1024, 256, 0, stream>>>(Wo, wot);

  // 1) frame QKV
  gemm256<bf16, 6><<<1536, 512, 0, stream>>>(xb, wfb, bfb, qkv);
  // 2) frame attention (keys = 128 frames)
  attn2<8, 0, 136><<<4096, 256, 0, stream>>>(qkv, fa);
  // 3) point QKV
  gemm256<bf16, 6><<<1536, 512, 0, stream>>>(fa, wpb, bpb, qkv);
  // 4) point attention (keys = 256 points)
  attn2<16, 1, 272><<<4096, 256, 0, stream>>>(qkv, fa);
  // 5) out projection (fp32 out)
  gemm256<float, 2><<<512, 512, 0, stream>>>(fa, wot, bob, out);
}

// Round 2
// 741.777 us; speedup vs baseline: 1.0395x; 1.0039x over previous
//
#include <hip/hip_runtime.h>
#include <hip/hip_bf16.h>
#include <stdint.h>

typedef __bf16 bf16;
typedef __attribute__((ext_vector_type(8))) __bf16 bf16x8;
typedef __attribute__((ext_vector_type(4))) __bf16 bf16x4;
typedef __attribute__((ext_vector_type(4))) float f32x4;

#define B_ 2
#define F_ 128
#define P_ 256
#define H_ 8
#define D_ 64
#define DIM_ 512
#define NROWS (B_*F_*P_)   // 65536

// async global->LDS, 16B per lane. LDS dest must be wave-uniform base + lane*16.
__device__ __forceinline__ void load_lds16(const void* g, void* l) {
  __builtin_amdgcn_global_load_lds(
      (__attribute__((address_space(1))) void*)(uintptr_t)g,
      (__attribute__((address_space(3))) void*)(uint32_t)(uintptr_t)l,
      16, 0, 0);
}

// fp32 -> bf16 cast, 8 elements/thread (n must be a multiple of 8)
__global__ void cvt_f32_bf16(const float* __restrict__ src, bf16* __restrict__ dst, int n)
{
  int i = (blockIdx.x * 256 + threadIdx.x) * 8;
  if (i < n) {
    float4 a = *(const float4*)(src + i);
    float4 b = *(const float4*)(src + i + 4);
    bf16x8 o;
    o[0] = (bf16)a.x; o[1] = (bf16)a.y; o[2] = (bf16)a.z; o[3] = (bf16)a.w;
    o[4] = (bf16)b.x; o[5] = (bf16)b.y; o[6] = (bf16)b.z; o[7] = (bf16)b.w;
    *(bf16x8*)(dst + i) = o;
  }
}

// W_o fp32 [512(he)][512(d)] -> wot bf16 [512(d)][512(he)]
__global__ void transpose_wo(const float* __restrict__ src, bf16* __restrict__ dst)
{
  int idx = blockIdx.x * 256 + threadIdx.x;
  int d = idx & 511, he = idx >> 9;
  dst[(size_t)d * 512 + he] = (bf16)src[(size_t)he * 512 + d];
}

// ---------------------------------------------------------------------------
// gemm256: C[M x N] = A[M x K=512] * Bt[N x K]^T + bias[N]
// 256x256 tile, BK=32, 8 waves (2M x 4N), 512 threads, 128 KiB LDS.
// Schedule (this round): register-level software pipeline. The 12 ds_read_b128
// per K-tile are issued one phase AHEAD (6 after bar1, 6 after bar2) so they
// overlap the other phase's 16-MFMA cluster. Staging depth 3 with counted
// vmcnt (8/4/0); 2 barriers per K-tile; sched_barrier(0) pins load issue.
// LDS k-octet swizzle g(row)=(row>>1)&3 (0 conflicts, verified round 1).
// XCD-chunked block swizzle, N-fast within chunk.
// ---------------------------------------------------------------------------
template <typename OutT, int NT>
__global__ __launch_bounds__(512, 2)
void gemm256(const bf16* __restrict__ A, const bf16* __restrict__ Bt,
             const float* __restrict__ bias, OutT* __restrict__ C)
{
  constexpr int K = 512;
  constexpr int N = NT * 256;
  constexpr int NTILES = 16;              // K / 32
  __shared__ __align__(16) bf16 As[4][256 * 32];
  __shared__ __align__(16) bf16 Bs[4][256 * 32];

  const int t    = threadIdx.x;
  const int lane = t & 63;
  const int l16  = lane & 15;
  const int qd   = lane >> 4;
  const int wave = t >> 6;
  const int wm   = wave >> 2;             // 0..1  (M half)
  const int wn   = wave & 3;              // 0..3  (N quarter)

  // XCD-aware swizzle: NWG/8 consecutive logical blocks per XCD, N-fast.
  constexpr int NWG = NT * 256;
  const int logical = (blockIdx.x & 7) * (NWG / 8) + (blockIdx.x >> 3);
  const int mBase = (logical / NT) * 256;
  const int nBase = (logical % NT) * 256;

  // staging: slot c = r*512 + t (16B each), row = c>>2 (+128 for r=1),
  // global k-octet pre-swizzled by g(row) = (row>>1)&3 (same for both r).
  const int srow = t >> 2;
  const int soct = (((t & 3) ^ ((srow >> 1) & 3)) << 3);
  const bf16* aS0 = A  + (size_t)(mBase + srow)       * K + soct;
  const bf16* aS1 = A  + (size_t)(mBase + srow + 128) * K + soct;
  const bf16* bS0 = Bt + (size_t)(nBase + srow)       * K + soct;
  const bf16* bS1 = Bt + (size_t)(nBase + srow + 128) * K + soct;
  const int dst = t * 8;                  // elems; *2B = lane-linear 16B slots

#define STAGE(tt) do { \
    load_lds16(aS0 + (tt) * 32, &As[(tt) & 3][dst]); \
    load_lds16(aS1 + (tt) * 32, &As[(tt) & 3][4096 + dst]); \
    load_lds16(bS0 + (tt) * 32, &Bs[(tt) & 3][dst]); \
    load_lds16(bS1 + (tt) * 32, &Bs[(tt) & 3][4096 + dst]); } while (0)

  // fragment read: row = (warp rows) + l16, octet qd, swizzled by g(row);
  // g(row) reduces to (l16>>1)&3 for every fragment (other terms ≡0 mod 4).
  const int swz = ((qd ^ ((l16 >> 1) & 3)) << 3);
  const bf16* aRd = &As[0][(wm * 128 + l16) * 32 + swz];
  const bf16* bRd = &Bs[0][(wn * 64  + l16) * 32 + swz];

  f32x4 acc[8][4] = {};
  bf16x8 la[2][4], lb[2][4], ha[2][4];    // double-buffered fragments

#define MF(i, j, av, bv) \
  acc[i][j] = __builtin_amdgcn_mfma_f32_16x16x32_bf16(av, bv, acc[i][j], 0, 0, 0)

  // prologue: stage tiles 0..2 (12 gloads/thread in flight)
  STAGE(0); STAGE(1); STAGE(2);
  asm volatile("s_waitcnt vmcnt(8)" ::: "memory");  // tile 0 landed
  __builtin_amdgcn_s_barrier();
  asm volatile("" ::: "memory");
  __builtin_amdgcn_sched_barrier(0);
  // initial fragments for tile 0
#pragma unroll
  for (int j = 0; j < 4; ++j) lb[0][j] = *(const bf16x8*)(bRd + j * 512);
#pragma unroll
  for (int i = 0; i < 4; ++i) la[0][i] = *(const bf16x8*)(aRd + i * 512);
#pragma unroll
  for (int i = 0; i < 4; ++i) ha[0][i] = *(const bf16x8*)(aRd + (4 + i) * 512);
  __builtin_amdgcn_sched_barrier(0);

#pragma unroll
  for (int tt = 0; tt < NTILES; ++tt) {
    const int cur = tt & 1, nxt = cur ^ 1;
    const bf16* aN = aRd + ((tt + 1) & 3) * (256 * 32);
    const bf16* bN = bRd + ((tt + 1) & 3) * (256 * 32);

    // stage tile tt+3 into buffer (tt+3)&3 = (tt-1)&3 (safe: all waves passed
    // bar2(tt-1), by which their buffer tt-1 reads had completed).
    if (tt + 3 < NTILES) STAGE(tt + 3);

    // ---- phase A: 16 MFMA on la[cur] x lb[cur] (ha[cur] still in flight) ----
    __builtin_amdgcn_s_setprio(1);
#pragma unroll
    for (int i = 0; i < 4; ++i)
#pragma unroll
      for (int j = 0; j < 4; ++j) MF(i, j, la[cur][i], lb[cur][j]);
    __builtin_amdgcn_s_setprio(0);

    if (tt + 1 < NTILES) {
      // buffer tt+1 ready: counted vmcnt (tiles tt+2, tt+3 stay in flight)
      if      (tt <= NTILES - 4) asm volatile("s_waitcnt vmcnt(8)" ::: "memory");
      else if (tt == NTILES - 3) asm volatile("s_waitcnt vmcnt(4)" ::: "memory");
      else                       asm volatile("s_waitcnt vmcnt(0)" ::: "memory");
      __builtin_amdgcn_s_barrier();
      asm volatile("" ::: "memory");
      __builtin_amdgcn_sched_barrier(0);
      // issue 6 reads for tile tt+1; they complete under phase B's MFMAs
#pragma unroll
      for (int j = 0; j < 4; ++j) lb[nxt][j] = *(const bf16x8*)(bN + j * 512);
      la[nxt][0] = *(const bf16x8*)(aN);
      la[nxt][1] = *(const bf16x8*)(aN + 512);
      __builtin_amdgcn_sched_barrier(0);
    }

    // ---- phase B: 16 MFMA on ha[cur] x lb[cur] ----
    __builtin_amdgcn_s_setprio(1);
#pragma unroll
    for (int i = 0; i < 4; ++i)
#pragma unroll
      for (int j = 0; j < 4; ++j) MF(4 + i, j, ha[cur][i], lb[cur][j]);
    __builtin_amdgcn_s_setprio(0);

    if (tt + 1 < NTILES) {
      __builtin_amdgcn_s_barrier();
      asm volatile("" ::: "memory");
      __builtin_amdgcn_sched_barrier(0);
      // issue remaining 6 reads for tile tt+1; complete under next phase A
      la[nxt][2] = *(const bf16x8*)(aN + 2 * 512);
      la[nxt][3] = *(const bf16x8*)(aN + 3 * 512);
#pragma unroll
      for (int i = 0; i < 4; ++i) ha[nxt][i] = *(const bf16x8*)(aN + (4 + i) * 512);
      __builtin_amdgcn_sched_barrier(0);
    }
  }
#undef STAGE
#undef MF

  // epilogue: D row = qd*4 + r within each 16x16 tile, col = l16
#pragma unroll
  for (int j = 0; j < 4; ++j) {
    const int coln = nBase + wn * 64 + j * 16 + l16;
    const float bv = bias[coln];
#pragma unroll
    for (int i = 0; i < 8; ++i) {
      const int rowm = mBase + wm * 128 + i * 16 + qd * 4;
#pragma unroll
      for (int r = 0; r < 4; ++r)
        C[(size_t)(rowm + r) * N + coln] = (OutT)(acc[i][j][r] + bv);
    }
  }
}

// ---------------------------------------------------------------------------
// Attention v2: S^T = K·Q^T (C layout: row=key, col=q), softmax in registers,
// O^T = V^T·P^T. Q/K fragments loaded straight from global (b128, no LDS).
// LDS: Vt[64][VS] (V transposed, padded) + Pq[128][136] (wave-private P rows).
// One __syncthreads total. NKT = key tiles of 16 (8 frame / 16 point).
// ---------------------------------------------------------------------------
template <int NKT, int MODE, int VS>
__global__ __launch_bounds__(256, 2)
void attn2(const bf16* __restrict__ qkv, bf16* __restrict__ outp)
{
  __shared__ __align__(16) bf16 Vt[64 * VS];
  __shared__ __align__(16) bf16 Pq[128 * 136];

  const int t    = threadIdx.x;
  const int lane = t & 63;
  const int wave = t >> 6;
  const int l16  = lane & 15;
  const int qd   = lane >> 4;

  const int bid = blockIdx.x;
  int h, q0, rowbase, rstride;
  if (MODE == 0) {
    h = bid & 7;
    int p = (bid >> 3) & (P_ - 1);
    int b = bid >> 11;
    rowbase = b * F_ * P_ + p; rstride = P_; q0 = 0;
  } else {
    int qb = bid & 1;
    h = (bid >> 1) & 7;
    int f = (bid >> 4) & (F_ - 1);
    int b = bid >> 11;
    rowbase = (b * F_ + f) * P_; rstride = 1; q0 = qb * 128;
  }

  // ---- stage V^T into LDS: Vt[e][key], padded stride VS ----
#pragma unroll
  for (int p = 0; p < NKT / 8; ++p) {
    int key = p * 128 + (t >> 1);
    int eh  = (t & 1) * 32;
    const bf16* src = qkv + (size_t)(rowbase + key * rstride) * 1536 + 1024 + h * 64 + eh;
    bf16x8 v[4];
#pragma unroll
    for (int jj = 0; jj < 4; ++jj) v[jj] = *(const bf16x8*)(src + jj * 8);
#pragma unroll
    for (int jj = 0; jj < 4; ++jj)
#pragma unroll
      for (int j = 0; j < 8; ++j)
        Vt[(eh + jj * 8 + j) * VS + key] = v[jj][j];
  }

  // ---- Q fragments (wave owns q columns wave*32..+31), direct global ----
  const int qloc = wave * 32;
  bf16x8 qf[2][2];
#pragma unroll
  for (int qt = 0; qt < 2; ++qt)
#pragma unroll
    for (int ks = 0; ks < 2; ++ks)
      qf[qt][ks] = *(const bf16x8*)(qkv +
          (size_t)(rowbase + (q0 + qloc + qt * 16 + l16) * rstride) * 1536 +
          h * 64 + ks * 32 + qd * 8);

  // ---- S^T = K·Q^T : K fragments direct from global ----
  f32x4 sacc[NKT][2] = {};
#pragma unroll
  for (int tn = 0; tn < NKT; ++tn) {
    const bf16* krow = qkv + (size_t)(rowbase + (tn * 16 + l16) * rstride) * 1536 + 512 + h * 64;
    bf16x8 kf0 = *(const bf16x8*)(krow + qd * 8);
    bf16x8 kf1 = *(const bf16x8*)(krow + 32 + qd * 8);
#pragma unroll
    for (int qt = 0; qt < 2; ++qt) {
      sacc[tn][qt] = __builtin_amdgcn_mfma_f32_16x16x32_bf16(kf0, qf[qt][0], sacc[tn][qt], 0, 0, 0);
      sacc[tn][qt] = __builtin_amdgcn_mfma_f32_16x16x32_bf16(kf1, qf[qt][1], sacc[tn][qt], 0, 0, 0);
    }
  }

  // ---- softmax over keys (rows of S^T): in-lane (tn,r) + shfl over qd ----
#pragma unroll
  for (int qt = 0; qt < 2; ++qt) {
    float m = -3.0e38f;
#pragma unroll
    for (int tn = 0; tn < NKT; ++tn)
#pragma unroll
      for (int r = 0; r < 4; ++r) m = fmaxf(m, sacc[tn][qt][r]);
    m = fmaxf(m, __shfl_xor(m, 16));
    m = fmaxf(m, __shfl_xor(m, 32));
    float s = 0.0f;
#pragma unroll
    for (int tn = 0; tn < NKT; ++tn)
#pragma unroll
      for (int r = 0; r < 4; ++r) {
        float e0 = __expf(sacc[tn][qt][r] - m);
        sacc[tn][qt][r] = e0;
        s += e0;
      }
    s += __shfl_xor(s, 16);
    s += __shfl_xor(s, 32);
    float inv = 1.0f / s;
#pragma unroll
    for (int tn = 0; tn < NKT; ++tn)
#pragma unroll
      for (int r = 0; r < 4; ++r) sacc[tn][qt][r] *= inv;
  }

  // ---- O^T = V^T·P^T, key-halves of 128; Pq rows are wave-private ----
  f32x4 oacc[4][2] = {};
#pragma unroll
  for (int hf = 0; hf < NKT / 8; ++hf) {
    // pack P rows (4 consecutive keys per lane) into Pq[q][key_local], b64
#pragma unroll
    for (int qt = 0; qt < 2; ++qt)
#pragma unroll
      for (int tl = 0; tl < 8; ++tl) {
        int tn = hf * 8 + tl;
        bf16x4 pk;
#pragma unroll
        for (int r = 0; r < 4; ++r) pk[r] = (bf16)sacc[tn][qt][r];
        *(bf16x4*)(Pq + (qloc + qt * 16 + l16) * 136 + tl * 16 + qd * 4) = pk;
      }
    if (hf == 0) __syncthreads();   // Vt ready; Pq needs no cross-wave sync
#pragma unroll
    for (int ks = 0; ks < 4; ++ks) {
      bf16x8 pf[2];
#pragma unroll
      for (int qt = 0; qt < 2; ++qt)
        pf[qt] = *(const bf16x8*)(Pq + (qloc + qt * 16 + l16) * 136 + ks * 32 + qd * 8);
#pragma unroll
      for (int te = 0; te < 4; ++te) {
        bf16x8 vf = *(const bf16x8*)(Vt + (te * 16 + l16) * VS + hf * 128 + ks * 32 + qd * 8);
#pragma unroll
        for (int qt = 0; qt < 2; ++qt)
          oacc[te][qt] = __builtin_amdgcn_mfma_f32_16x16x32_bf16(vf, pf[qt], oacc[te][qt], 0, 0, 0);
      }
    }
  }

  // ---- store O^T: lane holds rows e=te*16+qd*4..+3, col q -> b64 stores ----
#pragma unroll
  for (int te = 0; te < 4; ++te)
#pragma unroll
    for (int qt = 0; qt < 2; ++qt) {
      int q = q0 + qloc + qt * 16 + l16;
      bf16x4 pk;
#pragma unroll
      for (int r = 0; r < 4; ++r) pk[r] = (bf16)oacc[te][qt][r];
      *(bf16x4*)(outp + (size_t)(rowbase + q * rstride) * 512 + h * 64 + te * 16 + qd * 4) = pk;
    }
}

extern "C" void kernel_launch(void* const* d_in, const int* in_sizes, int n_in,
                              void* d_out, int out_size, void* d_ws, size_t ws_size,
                              hipStream_t stream)
{
  (void)in_sizes; (void)n_in; (void)out_size; (void)ws_size;
  const float* x   = (const float*)d_in[0];   // [B,F,P,512] fp32
  const float* Wf  = (const float*)d_in[1];   // [3,8,64,512] fp32
  const float* bfb = (const float*)d_in[2];   // [1536] fp32
  const float* Wp  = (const float*)d_in[3];   // [3,8,64,8,64] fp32
  const float* bpb = (const float*)d_in[4];   // [1536] fp32
  const float* Wo  = (const float*)d_in[5];   // [8,64,512] fp32
  const float* bob = (const float*)d_in[6];   // [512] fp32
  float* out = (float*)d_out;                 // fp32 output

  char* ws = (char*)d_ws;
  bf16* qkv = (bf16*)ws;                                   // 65536x1536 (reused)
  bf16* fa  = (bf16*)(ws + (size_t)NROWS * 1536 * 2);      // 65536x512 (xb/fa/pa)
  bf16* xb  = fa;
  char* wbase = ws + (size_t)NROWS * 1536 * 2 + (size_t)NROWS * 512 * 2;
  bf16* wfb = (bf16*)wbase;
  bf16* wpb = (bf16*)(wbase + 1536 * 512 * 2);
  bf16* wot = (bf16*)(wbase + 2 * 1536 * 512 * 2);

  cvt_f32_bf16<<<(NROWS * 512) / (256 * 8), 256, 0, stream>>>(x, xb, NROWS * 512);
  cvt_f32_bf16<<<(1536 * 512) / (256 * 8), 256, 0, stream>>>(Wf, wfb, 1536 * 512);
  cvt_f32_bf16<<<(1536 * 512) / (256 * 8), 256, 0, stream>>>(Wp, wpb, 1536 * 512);
  transpose_wo<<<1024, 256, 0, stream>>>(Wo, wot);

  // 1) frame QKV
  gemm256<bf16, 6><<<1536, 512, 0, stream>>>(xb, wfb, bfb, qkv);
  // 2) frame attention (keys = 128 frames)
  attn2<8, 0, 136><<<4096, 256, 0, stream>>>(qkv, fa);
  // 3) point QKV
  gemm256<bf16, 6><<<1536, 512, 0, stream>>>(fa, wpb, bpb, qkv);
  // 4) point attention (keys = 256 points)
  attn2<16, 1, 272><<<4096, 256, 0, stream>>>(qkv, fa);
  // 5) out projection (fp32 out)
  gemm256<float, 2><<<512, 512, 0, stream>>>(fa, wot, bob, out);
}